// Round 14
// baseline (150.910 us; speedup 1.0000x reference)
//
#include <hip/hip_runtime.h>
#include <hip/hip_bf16.h>
#include <stdint.h>

typedef __attribute__((ext_vector_type(8))) short short8;
typedef __attribute__((ext_vector_type(4))) float f32x4;

#define NROWS  8192
#define DDIM   256
#define HHEADS 4
#define KTOT   1024
#define BM     128
#define BN     128
#define BK     32
#define NT     (KTOT / BK)        // 32 K-tiles
#define NTB    (NROWS / BM)       // 64 tile rows
#define NJOBS  (NTB * (NTB + 1) / 2)   // 2080 = 8 * 260
#define BUFE   8192               // elems per K-tile buf: A 4096 + B 4096 (16 KB)

#define SBAR()  __builtin_amdgcn_s_barrier()
#define LGKM0() do { asm volatile("s_waitcnt lgkmcnt(0)" ::: "memory"); \
                     __builtin_amdgcn_sched_barrier(0); } while (0)
#define VMCNT(n) do { asm volatile("s_waitcnt vmcnt(" #n ")" ::: "memory"); \
                      __builtin_amdgcn_sched_barrier(0); } while (0)

__device__ __forceinline__ unsigned short f2bf(float f) {
  union { float f; uint32_t u; } v;
  v.f = f;
  uint32_t u = v.u;
  uint32_t r = (u + 0x7fffu + ((u >> 16) & 1u)) >> 16;
  return (unsigned short)r;
}

// --------------------------------------------------------------------------
// Kernel 1: Y[n, h*256+d] = bf16-normalized per-head scaled rows
// --------------------------------------------------------------------------
__global__ __launch_bounds__(256) void prep_y(const float* __restrict__ x,
                                              const float* __restrict__ av,
                                              unsigned short* __restrict__ Y) {
  __shared__ float a_sh[HHEADS][DDIM];
  __shared__ float red[4][HHEADS];

  const int t = threadIdx.x;
  #pragma unroll
  for (int h = 0; h < HHEADS; ++h) a_sh[h][t] = av[h * DDIM + t];
  __syncthreads();

  const int n = blockIdx.x;
  const float xd = x[(size_t)n * DDIM + t];

  float p[HHEADS], s[HHEADS];
  #pragma unroll
  for (int h = 0; h < HHEADS; ++h) { p[h] = a_sh[h][t] * xd; s[h] = p[h] * p[h]; }

  #pragma unroll
  for (int off = 32; off > 0; off >>= 1) {
    #pragma unroll
    for (int h = 0; h < HHEADS; ++h) s[h] += __shfl_xor(s[h], off, 64);
  }

  const int wave = t >> 6, lane = t & 63;
  if (lane == 0) {
    #pragma unroll
    for (int h = 0; h < HHEADS; ++h) red[wave][h] = s[h];
  }
  __syncthreads();

  #pragma unroll
  for (int h = 0; h < HHEADS; ++h) {
    const float sum = red[0][h] + red[1][h] + red[2][h] + red[3][h];
    const float rn = rsqrtf(fmaxf(sum, 1e-12f));
    Y[(size_t)n * KTOT + h * DDIM + t] = f2bf(p[h] * rn);
  }
}

// --------------------------------------------------------------------------
// stage one 16 KB K-tile (A 128x32 + B 128x32 bf16): 4 global_load_lds(16B)
// per thread (256 threads).  Linear LDS dest; add-rotate swizzle
// slot' = (slot + (row>>1)) & 3 applied on the GLOBAL source (rule #21):
// the ds_read at slot (lh + (row>>1)) & 3 then yields chunk lh.
// --------------------------------------------------------------------------
__device__ __forceinline__ void stage_tile(const unsigned short* __restrict__ Y,
                                           unsigned short* buf,
                                           int rowA0, int rowB0, int k0, int tid) {
  #pragma unroll
  for (int i = 0; i < 2; ++i) {                    // A region: 512 slots
    const int s   = i * 256 + tid;
    const int r   = s >> 2;                        // 0..127
    const int gsl = ((s & 3) + 4 - ((r >> 1) & 3)) & 3;
    const unsigned short* gsrc = Y + (size_t)(rowA0 + r) * KTOT + k0 + gsl * 8;
    __builtin_amdgcn_global_load_lds(
        (const __attribute__((address_space(1))) void*)gsrc,
        (__attribute__((address_space(3))) void*)(buf + s * 8), 16, 0, 0);
  }
  #pragma unroll
  for (int i = 0; i < 2; ++i) {                    // B region: 512 slots
    const int s   = i * 256 + tid;
    const int r   = s >> 2;
    const int gsl = ((s & 3) + 4 - ((r >> 1) & 3)) & 3;
    const unsigned short* gsrc = Y + (size_t)(rowB0 + r) * KTOT + k0 + gsl * 8;
    __builtin_amdgcn_global_load_lds(
        (const __attribute__((address_space(1))) void*)gsrc,
        (__attribute__((address_space(3))) void*)(buf + 4096 + s * 8), 16, 0, 0);
  }
}

// --------------------------------------------------------------------------
// Kernel 2: C = Y*Y^T / 4 on 128x128 triangular tiles (by >= bx), 4 waves,
// each wave 64x64 out (acc[4][4] = 64 VGPR; total ~121 — SAFELY under the
// 170-VGPR/wave budget at 3 waves/SIMD so 3 blocks/CU co-residency is
// guaranteed; r1-r13's plateau is consistent with register pressure silently
// capping co-residency at 1-2 blocks).  Tri-buffered BK=32, counted vmcnt.
// Ledger per K-tile T: issue stage(T+2 -> buf[(T+2)%3]) (4 loads);
// ds_read frags from buf[T%3]; lgkmcnt(0); 16 MFMA; vmcnt(4) (T+1 landed,
// T+2's 4 loads in flight); s_barrier.
// --------------------------------------------------------------------------
__global__ __launch_bounds__(256, 3) void gemm_yyt(const unsigned short* __restrict__ Y,
                                                   float* __restrict__ C) {
  __shared__ __attribute__((aligned(16))) unsigned short lds[3 * BUFE];  // 48 KB

  // bijective XCD swizzle: 2080 = 8 * 260
  const int orig = blockIdx.x;
  const int wg   = (orig & 7) * (NJOBS / 8) + (orig >> 3);

  // triangular decode: wg -> (by, bx), bx <= by
  int by = (int)((sqrtf(8.0f * (float)wg + 1.0f) - 1.0f) * 0.5f);
  while ((by + 1) * (by + 2) / 2 <= wg) ++by;
  while (by * (by + 1) / 2 > wg) --by;
  const int bx = wg - by * (by + 1) / 2;

  const int rowA0 = by * BM;
  const int rowB0 = bx * BN;
  const bool mirror = (by != bx);

  const int tid  = threadIdx.x;
  const int lane = tid & 63;
  const int wv   = tid >> 6;      // 0..3
  const int wr   = wv >> 1;       // 0..1 (M half)
  const int wn   = wv & 1;        // 0..1 (N half)
  const int l15  = lane & 15;
  const int lh   = lane >> 4;     // 0..3

  f32x4 acc[4][4];
  #pragma unroll
  for (int m = 0; m < 4; ++m)
    #pragma unroll
    for (int n = 0; n < 4; ++n) acc[m][n] = (f32x4){0.f, 0.f, 0.f, 0.f};

  // prologue: stage K-tiles 0 and 1
  stage_tile(Y, lds + 0,    rowA0, rowB0, 0,  tid);
  stage_tile(Y, lds + BUFE, rowA0, rowB0, BK, tid);
  VMCNT(4);    // tile 0 landed; tile 1's 4 loads may fly
  SBAR();
  __builtin_amdgcn_sched_barrier(0);

  int cur = 0;
  int nx2 = 2 * BUFE;
  short8 af[4], bf[4];

  for (int T = 0; T < NT; ++T) {
    if (T + 2 < NT) stage_tile(Y, lds + nx2, rowA0, rowB0, (T + 2) * BK, tid);

    #pragma unroll
    for (int m = 0; m < 4; ++m) {
      const int r_ = wr * 64 + m * 16 + l15;
      const int sl = (lh + ((r_ >> 1) & 3)) & 3;
      af[m] = *(const short8*)(lds + cur + r_ * 32 + sl * 8);
    }
    #pragma unroll
    for (int n = 0; n < 4; ++n) {
      const int r_ = wn * 64 + n * 16 + l15;
      const int sl = (lh + ((r_ >> 1) & 3)) & 3;
      bf[n] = *(const short8*)(lds + cur + 4096 + r_ * 32 + sl * 8);
    }
    __builtin_amdgcn_sched_barrier(0);
    LGKM0();

    __builtin_amdgcn_s_setprio(1);
    #pragma unroll
    for (int m = 0; m < 4; ++m)
      #pragma unroll
      for (int n = 0; n < 4; ++n)
        acc[m][n] = __builtin_amdgcn_mfma_f32_16x16x32_bf16(
            af[m], bf[n], acc[m][n], 0, 0, 0);
    __builtin_amdgcn_s_setprio(0);
    __builtin_amdgcn_sched_barrier(0);

    if (T < NT - 2)       { VMCNT(4); }   // T+1 landed; T+2 in flight
    else if (T == NT - 2) { VMCNT(0); }   // last prefetch (T+1) landed
    SBAR();

    cur += BUFE; if (cur == 3 * BUFE) cur = 0;
    nx2 += BUFE; if (nx2 == 3 * BUFE) nx2 = 0;
  }

  // ---- straight write (direct; r13 showed LDS-staging this is neutral) ----
  const int crow0 = rowA0 + wr * 64;
  const int ccol  = rowB0 + wn * 64 + l15;
  #pragma unroll
  for (int m = 0; m < 4; ++m)
    #pragma unroll
    for (int n = 0; n < 4; ++n)
      #pragma unroll
      for (int r = 0; r < 4; ++r) {
        const int row = crow0 + m * 16 + lh * 4 + r;
        C[(size_t)row * NROWS + ccol + n * 16] = acc[m][n][r] * 0.25f;
      }

  // ---- mirror write via LDS transpose (off-diagonal tiles only) ----
  // stores are full-line f32x4; acc[m][n][0..3] = 4 consecutive rl -> one
  // ds_write_b128 each.  tr stride 132 keeps 16B alignment, 2-way banks.
  if (mirror) {
    float (*tr)[132] = (float(*)[132])lds;   // 32 x 132 f32 = 16.9 KB
    #pragma unroll
    for (int s = 0; s < 4; ++s) {            // col slices of 32
      if (s > 0) SBAR();                     // previous slice readers done
      if (wn == (s >> 1)) {
        const int ns = 2 * (s & 1);
        #pragma unroll
        for (int nn = 0; nn < 2; ++nn)
          #pragma unroll
          for (int m = 0; m < 4; ++m) {
            const int cl  = nn * 16 + l15;                 // 0..31
            const int rl0 = wr * 64 + m * 16 + lh * 4;     // 0..124, %4==0
            *(f32x4*)&tr[cl][rl0] = acc[m][ns + nn];
          }
        LGKM0();                             // my ds_writes visible
      }
      SBAR();
      #pragma unroll
      for (int q = 0; q < 4; ++q) {
        const int idx = q * 256 + tid;       // 0..1023 over 32x32 f32x4
        const int ii  = idx >> 5;            // 0..31
        const int jj  = (idx & 31) * 4;      // 0..124
        f32x4 v = *(const f32x4*)&tr[ii][jj];
        v *= 0.25f;
        *(f32x4*)(C + (size_t)(rowB0 + s * 32 + ii) * NROWS + rowA0 + jj) = v;
      }
    }
  }
}

// --------------------------------------------------------------------------
extern "C" void kernel_launch(void* const* d_in, const int* in_sizes, int n_in,
                              void* d_out, int out_size, void* d_ws, size_t ws_size,
                              hipStream_t stream) {
  (void)in_sizes; (void)n_in; (void)out_size; (void)ws_size;
  const float* x  = (const float*)d_in[0];   // [8192, 256] f32
  const float* av = (const float*)d_in[1];   // [4, 256] f32
  float* C = (float*)d_out;                  // [8192, 8192] f32
  unsigned short* Y = (unsigned short*)d_ws; // [8192, 1024] bf16 scratch (16 MiB)

  prep_y<<<NROWS, 256, 0, stream>>>(x, av, Y);
  gemm_yyt<<<NJOBS, 256, 0, stream>>>(Y, C);
}

// Round 15
// 123.827 us; speedup vs baseline: 1.2187x; 1.2187x over previous
//
#include <hip/hip_runtime.h>
#include <hip/hip_bf16.h>
#include <stdint.h>

typedef __attribute__((ext_vector_type(8))) short short8;
typedef __attribute__((ext_vector_type(4))) float f32x4;

#define NROWS  8192
#define DDIM   256
#define HHEADS 4
#define KTOT   1024
#define BM     128
#define BN     128
#define BK     32
#define NT     (KTOT / BK)        // 32 K-tiles
#define NTB    (NROWS / BM)       // 64 tile rows -> 8 super-rows of 8
#define BUFE   8192               // elems per K-tile buf: A 4096 + B 4096 (16 KB)
#define GRID   2112               // 8 XCDs x 264 slots (32 no-op blocks)

#define SBAR()  __builtin_amdgcn_s_barrier()
#define LGKM0() do { asm volatile("s_waitcnt lgkmcnt(0)" ::: "memory"); \
                     __builtin_amdgcn_sched_barrier(0); } while (0)
#define VMCNT(n) do { asm volatile("s_waitcnt vmcnt(" #n ")" ::: "memory"); \
                      __builtin_amdgcn_sched_barrier(0); } while (0)

// Supertile -> XCD assignment (supertile = 8x8 tiles; 16 panels = 4 MB = one
// XCD L2).  code = I*8+J (J<=I; diagonal iff code%9==0).  Load-balanced:
// xcd 0-3: 4 full supers (256 jobs); xcd 4-7: 3 full + 2 diag (264 jobs).
__constant__ int SUPTAB[8][5] = {
  { 8, 16, 17, 24, -1},
  {25, 26, 32, 33, -1},
  {34, 35, 40, 41, -1},
  {42, 43, 44, 48, -1},
  {49, 50, 51,  0,  9},
  {52, 53, 56, 18, 27},
  {57, 58, 59, 36, 45},
  {60, 61, 62, 54, 63},
};

__device__ __forceinline__ unsigned short f2bf(float f) {
  union { float f; uint32_t u; } v;
  v.f = f;
  uint32_t u = v.u;
  uint32_t r = (u + 0x7fffu + ((u >> 16) & 1u)) >> 16;
  return (unsigned short)r;
}

// --------------------------------------------------------------------------
// Kernel 1: Y[n, h*256+d] = bf16-normalized per-head scaled rows
// --------------------------------------------------------------------------
__global__ __launch_bounds__(256) void prep_y(const float* __restrict__ x,
                                              const float* __restrict__ av,
                                              unsigned short* __restrict__ Y) {
  __shared__ float a_sh[HHEADS][DDIM];
  __shared__ float red[4][HHEADS];

  const int t = threadIdx.x;
  #pragma unroll
  for (int h = 0; h < HHEADS; ++h) a_sh[h][t] = av[h * DDIM + t];
  __syncthreads();

  const int n = blockIdx.x;
  const float xd = x[(size_t)n * DDIM + t];

  float p[HHEADS], s[HHEADS];
  #pragma unroll
  for (int h = 0; h < HHEADS; ++h) { p[h] = a_sh[h][t] * xd; s[h] = p[h] * p[h]; }

  #pragma unroll
  for (int off = 32; off > 0; off >>= 1) {
    #pragma unroll
    for (int h = 0; h < HHEADS; ++h) s[h] += __shfl_xor(s[h], off, 64);
  }

  const int wave = t >> 6, lane = t & 63;
  if (lane == 0) {
    #pragma unroll
    for (int h = 0; h < HHEADS; ++h) red[wave][h] = s[h];
  }
  __syncthreads();

  #pragma unroll
  for (int h = 0; h < HHEADS; ++h) {
    const float sum = red[0][h] + red[1][h] + red[2][h] + red[3][h];
    const float rn = rsqrtf(fmaxf(sum, 1e-12f));
    Y[(size_t)n * KTOT + h * DDIM + t] = f2bf(p[h] * rn);
  }
}

// --------------------------------------------------------------------------
// stage one 16 KB K-tile (A 128x32 + B 128x32 bf16): 4 global_load_lds(16B)
// per thread (256 threads).  Linear LDS dest; add-rotate swizzle
// slot' = (slot + (row>>1)) & 3 applied on the GLOBAL source (rule #21).
// --------------------------------------------------------------------------
__device__ __forceinline__ void stage_tile(const unsigned short* __restrict__ Y,
                                           unsigned short* buf,
                                           int rowA0, int rowB0, int k0, int tid) {
  #pragma unroll
  for (int i = 0; i < 2; ++i) {                    // A region: 512 slots
    const int s   = i * 256 + tid;
    const int r   = s >> 2;                        // 0..127
    const int gsl = ((s & 3) + 4 - ((r >> 1) & 3)) & 3;
    const unsigned short* gsrc = Y + (size_t)(rowA0 + r) * KTOT + k0 + gsl * 8;
    __builtin_amdgcn_global_load_lds(
        (const __attribute__((address_space(1))) void*)gsrc,
        (__attribute__((address_space(3))) void*)(buf + s * 8), 16, 0, 0);
  }
  #pragma unroll
  for (int i = 0; i < 2; ++i) {                    // B region: 512 slots
    const int s   = i * 256 + tid;
    const int r   = s >> 2;
    const int gsl = ((s & 3) + 4 - ((r >> 1) & 3)) & 3;
    const unsigned short* gsrc = Y + (size_t)(rowB0 + r) * KTOT + k0 + gsl * 8;
    __builtin_amdgcn_global_load_lds(
        (const __attribute__((address_space(1))) void*)gsrc,
        (__attribute__((address_space(3))) void*)(buf + 4096 + s * 8), 16, 0, 0);
  }
}

// --------------------------------------------------------------------------
// Kernel 2: C = Y*Y^T / 4 on 128x128 triangular tiles, 4 waves, tri-buffered
// BK=32, 3 blocks/CU.  SUPERTILE SCHEDULING: 8x8-tile supertiles pinned to
// one XCD each (hardware round-robin xcd = blockIdx%8); a supertile's 16
// panels (4 MB) fit that XCD's L2, so panels are fetched over the L2-miss
// fabric once per supertile instead of once per block.  Theory: all rounds
// plateaued at L2-miss traffic / 9.7 TB/s (r12: 1.07GB/110us, r14:
// 1.33GB/137us); this cuts panel traffic ~5x.
// --------------------------------------------------------------------------
__global__ __launch_bounds__(256, 3) void gemm_yyt(const unsigned short* __restrict__ Y,
                                                   float* __restrict__ C) {
  __shared__ __attribute__((aligned(16))) unsigned short lds[3 * BUFE];  // 48 KB

  // ---- supertile job decode ----
  const int xcd = blockIdx.x & 7;
  int l = blockIdx.x >> 3;                    // local slot on this XCD
  if (l >= ((xcd < 4) ? 256 : 264)) return;   // 32 pad blocks exit

  int by = 0, bx = 0;
  #pragma unroll 1
  for (int k = 0; k < 5; ++k) {
    const int code = SUPTAB[xcd][k];
    const bool diag = (code % 9) == 0;
    const int cnt = diag ? 36 : 64;
    if (l < cnt) {
      const int I = code >> 3, J = code & 7;
      if (diag) {
        int ty = 0;
        while ((ty + 1) * (ty + 2) / 2 <= l) ++ty;
        const int tx = l - ty * (ty + 1) / 2;
        by = I * 8 + ty; bx = J * 8 + tx;
      } else {
        by = I * 8 + (l >> 3); bx = J * 8 + (l & 7);
      }
      break;
    }
    l -= cnt;
  }

  const int rowA0 = by * BM;
  const int rowB0 = bx * BN;
  const bool mirror = (by != bx);

  const int tid  = threadIdx.x;
  const int lane = tid & 63;
  const int wv   = tid >> 6;      // 0..3
  const int wr   = wv >> 1;       // 0..1 (M half)
  const int wn   = wv & 1;        // 0..1 (N half)
  const int l15  = lane & 15;
  const int lh   = lane >> 4;     // 0..3

  f32x4 acc[4][4];
  #pragma unroll
  for (int m = 0; m < 4; ++m)
    #pragma unroll
    for (int n = 0; n < 4; ++n) acc[m][n] = (f32x4){0.f, 0.f, 0.f, 0.f};

  // prologue: stage K-tiles 0 and 1
  stage_tile(Y, lds + 0,    rowA0, rowB0, 0,  tid);
  stage_tile(Y, lds + BUFE, rowA0, rowB0, BK, tid);
  VMCNT(4);    // tile 0 landed; tile 1's 4 loads may fly
  SBAR();
  __builtin_amdgcn_sched_barrier(0);

  int cur = 0;
  int nx2 = 2 * BUFE;
  short8 af[4], bf[4];

  for (int T = 0; T < NT; ++T) {
    if (T + 2 < NT) stage_tile(Y, lds + nx2, rowA0, rowB0, (T + 2) * BK, tid);

    #pragma unroll
    for (int m = 0; m < 4; ++m) {
      const int r_ = wr * 64 + m * 16 + l15;
      const int sl = (lh + ((r_ >> 1) & 3)) & 3;
      af[m] = *(const short8*)(lds + cur + r_ * 32 + sl * 8);
    }
    #pragma unroll
    for (int n = 0; n < 4; ++n) {
      const int r_ = wn * 64 + n * 16 + l15;
      const int sl = (lh + ((r_ >> 1) & 3)) & 3;
      bf[n] = *(const short8*)(lds + cur + 4096 + r_ * 32 + sl * 8);
    }
    __builtin_amdgcn_sched_barrier(0);
    LGKM0();

    __builtin_amdgcn_s_setprio(1);
    #pragma unroll
    for (int m = 0; m < 4; ++m)
      #pragma unroll
      for (int n = 0; n < 4; ++n)
        acc[m][n] = __builtin_amdgcn_mfma_f32_16x16x32_bf16(
            af[m], bf[n], acc[m][n], 0, 0, 0);
    __builtin_amdgcn_s_setprio(0);
    __builtin_amdgcn_sched_barrier(0);

    if (T < NT - 2)       { VMCNT(4); }   // T+1 landed; T+2 in flight
    else if (T == NT - 2) { VMCNT(0); }   // last prefetch (T+1) landed
    SBAR();

    cur += BUFE; if (cur == 3 * BUFE) cur = 0;
    nx2 += BUFE; if (nx2 == 3 * BUFE) nx2 = 0;
  }

  // ---- straight write (direct; LDS-staging it measured neutral, r13) ----
  const int crow0 = rowA0 + wr * 64;
  const int ccol  = rowB0 + wn * 64 + l15;
  #pragma unroll
  for (int m = 0; m < 4; ++m)
    #pragma unroll
    for (int n = 0; n < 4; ++n)
      #pragma unroll
      for (int r = 0; r < 4; ++r) {
        const int row = crow0 + m * 16 + lh * 4 + r;
        C[(size_t)row * NROWS + ccol + n * 16] = acc[m][n][r] * 0.25f;
      }

  // ---- mirror write via LDS transpose (off-diagonal tiles only) ----
  if (mirror) {
    float (*tr)[132] = (float(*)[132])lds;   // 32 x 132 f32 = 16.9 KB
    #pragma unroll
    for (int s = 0; s < 4; ++s) {            // col slices of 32
      if (s > 0) SBAR();                     // previous slice readers done
      if (wn == (s >> 1)) {
        const int ns = 2 * (s & 1);
        #pragma unroll
        for (int nn = 0; nn < 2; ++nn)
          #pragma unroll
          for (int m = 0; m < 4; ++m) {
            const int cl  = nn * 16 + l15;                 // 0..31
            const int rl0 = wr * 64 + m * 16 + lh * 4;     // 0..124, %4==0
            *(f32x4*)&tr[cl][rl0] = acc[m][ns + nn];
          }
        LGKM0();                             // my ds_writes visible
      }
      SBAR();
      #pragma unroll
      for (int q = 0; q < 4; ++q) {
        const int idx = q * 256 + tid;       // 0..1023 over 32x32 f32x4
        const int ii  = idx >> 5;            // 0..31
        const int jj  = (idx & 31) * 4;      // 0..124
        f32x4 v = *(const f32x4*)&tr[ii][jj];
        v *= 0.25f;
        *(f32x4*)(C + (size_t)(rowB0 + s * 32 + ii) * NROWS + rowA0 + jj) = v;
      }
    }
  }
}

// --------------------------------------------------------------------------
extern "C" void kernel_launch(void* const* d_in, const int* in_sizes, int n_in,
                              void* d_out, int out_size, void* d_ws, size_t ws_size,
                              hipStream_t stream) {
  (void)in_sizes; (void)n_in; (void)out_size; (void)ws_size;
  const float* x  = (const float*)d_in[0];   // [8192, 256] f32
  const float* av = (const float*)d_in[1];   // [4, 256] f32
  float* C = (float*)d_out;                  // [8192, 8192] f32
  unsigned short* Y = (unsigned short*)d_ws; // [8192, 1024] bf16 scratch (16 MiB)

  prep_y<<<NROWS, 256, 0, stream>>>(x, av, Y);
  gemm_yyt<<<GRID, 256, 0, stream>>>(Y, C);
}